// Round 13
// baseline (581.895 us; speedup 1.0000x reference)
//
#include <hip/hip_runtime.h>

#define NPTS 1000000
#define KOFF 27
#define KSTAGE 7                  // 4 LDS stages (7,7,7,6 k-offsets) -> 35 KB/block
#define CONV_BLOCK 256
#define ROWS_PER_BLOCK 128        // 4 waves x 32 rows
#define NWG_CONV 7813             // ceil(1e6/128)
#define NWAVES (NWG_CONV * 4)

typedef __bf16 bf16x8 __attribute__((ext_vector_type(8)));
typedef __bf16 bf16x4 __attribute__((ext_vector_type(4)));
typedef float f32x4 __attribute__((ext_vector_type(4)));

// ---------------- Kernel 1: xh[N][32] = bf16(feats)  (the ONLY gather target, 64 MB)
__global__ __launch_bounds__(256) void build_xh_kernel(
    const float* __restrict__ feats, __bf16* __restrict__ xh)
{
    const long g = (long)blockIdx.x * 256 + threadIdx.x;
    if (g >= (long)NPTS * 8) return;
    const int row = (int)(g >> 3);
    const int c = ((int)g & 7) << 2;
    f32x4 v = __builtin_nontemporal_load((const f32x4*)(feats + (size_t)row * 32 + c));
    bf16x4 o;
    o[0] = (__bf16)v[0]; o[1] = (__bf16)v[1];
    o[2] = (__bf16)v[2]; o[3] = (__bf16)v[3];
    *(bf16x4*)(xh + (size_t)row * 32 + c) = o;
}

// ---------------- Kernel 2 (merged prep): wlo / twc(compact 8-slot) / bounds
__global__ __launch_bounds__(256) void prep_kernel(
    const float* __restrict__ W, const float* __restrict__ time_emb,
    const int* __restrict__ batch_idx,
    __bf16* __restrict__ wlo, __bf16* __restrict__ twc, int* __restrict__ bounds)
{
    const int b = blockIdx.x;
    if (b < 216) {
        // wlo[k][cout][cin0..31]
        const int g = b * 256 + threadIdx.x;
        const int k = g >> 11, rem = g & 2047;
        const int co = rem >> 5, ci = rem & 31;
        wlo[g] = (__bf16)W[k * 4096 + ci * 64 + co];
    } else if (b < 270) {
        // twc[k][cout][slot0..7] = time_emb[slot]·W[k][32:,cout]
        const int g = (b - 216) * 256 + threadIdx.x;
        if (g >= KOFF * 512) return;
        const int k = g >> 9, rem = g & 511;
        const int co = rem >> 3, slot = rem & 7;
        float v = 0.f;
#pragma unroll
        for (int ci = 0; ci < 32; ++ci)
            v += time_emb[slot * 32 + ci] * W[k * 4096 + (32 + ci) * 64 + co];
        twc[g] = (__bf16)v;
    } else {
        const int j = threadIdx.x;
        if (j > 8) return;
        if (j == 0) { bounds[0] = 0; return; }
        if (j == 8) { bounds[8] = NPTS; return; }
        int lo = 0, hi = NPTS;
        while (lo < hi) {
            const int mid = (lo + hi) >> 1;
            if (batch_idx[mid] < j) lo = mid + 1; else hi = mid;
        }
        bounds[j] = lo;
    }
}

__device__ __forceinline__ int batch_of(int g, int t1, int t2, int t3, int t4,
                                        int t5, int t6, int t7)
{
    return (g >= t1) + (g >= t2) + (g >= t3) + (g >= t4) +
           (g >= t5) + (g >= t6) + (g >= t7);
}

// ---------------- Kernel 3: gather-GEMM conv.
// r13 = r12 with KSTAGE 9->7: LDS 35 KB/block -> 4 blocks/CU = 16 waves/CU (the
// VGPR-84 cap). One extra restage. Occupancy-curve continuation experiment.
// All weight/tw reads are LDS (lgkmcnt: never drains the vmcnt gather queue).
// X gather ring dist 4 (8 gather-instr in flight/wave), idx ring dist 8.
template <int BF16PRE>
__global__ __launch_bounds__(CONV_BLOCK, 2) void conv_kernel(
    const __bf16* __restrict__ xh, const int* __restrict__ bounds,
    const __bf16* __restrict__ wlo, const __bf16* __restrict__ twc,
    const int* __restrict__ nbr_idx, const int* __restrict__ nbr_valid,
    float* __restrict__ outf, __bf16* __restrict__ pre,
    float* __restrict__ partials)
{
    __shared__ __bf16 w_lds[KSTAGE * 2048];   // 28 KB: [kk][cout][cin0..31]
    __shared__ __bf16 t_lds[KSTAGE * 512];    // 7 KB:  [kk][cout][slot0..7]

    const int tid  = threadIdx.x;
    const int wave = tid >> 6;
    const int lane = tid & 63;
    const int l15  = lane & 15;
    const int quad = lane >> 4;
    const int R0   = blockIdx.x * ROWS_PER_BLOCK + wave * 32;
    const int row0 = R0 + l15;
    const int row1 = row0 + 16;
    const bool ok0 = row0 < NPTS;
    const bool ok1 = row1 < NPTS;
    const int r0c = ok0 ? row0 : NPTS - 1;
    const int r1c = ok1 ? row1 : NPTS - 1;

    auto stage = [&](int k0) {
        const int cnt = (KOFF - k0 < KSTAGE) ? (KOFF - k0) : KSTAGE;  // tail guard
        const bf16x8* wsrc = (const bf16x8*)wlo + (size_t)k0 * 256;
        bf16x8* wdst = (bf16x8*)w_lds;
#pragma unroll
        for (int i = 0; i < 7; ++i) {             // up to 1792 chunks / 256 threads
            const int c = tid + i * CONV_BLOCK;
            if (c < cnt * 256) wdst[c] = wsrc[c];
        }
        const bf16x8* tsrc = (const bf16x8*)twc + (size_t)k0 * 64;
        bf16x8* tdst = (bf16x8*)t_lds;
#pragma unroll
        for (int i = 0; i < 2; ++i) {             // up to 448 chunks / 256 threads
            const int c = tid + i * CONV_BLOCK;
            if (c < cnt * 64) tdst[c] = tsrc[c];
        }
    };

    stage(0);
    __syncthreads();

    const int t1 = __builtin_amdgcn_readfirstlane(bounds[1]);
    const int t2 = __builtin_amdgcn_readfirstlane(bounds[2]);
    const int t3 = __builtin_amdgcn_readfirstlane(bounds[3]);
    const int t4 = __builtin_amdgcn_readfirstlane(bounds[4]);
    const int t5 = __builtin_amdgcn_readfirstlane(bounds[5]);
    const int t6 = __builtin_amdgcn_readfirstlane(bounds[6]);
    const int t7 = __builtin_amdgcn_readfirstlane(bounds[7]);

    f32x4 acc[2][4];
#pragma unroll
    for (int m = 0; m < 2; ++m)
#pragma unroll
        for (int ct = 0; ct < 4; ++ct)
            acc[m][ct] = (f32x4){0.f, 0.f, 0.f, 0.f};

    bf16x8 X0[5], X1[5];                  // gathered feat fragments, ring 5 (dist 4)
    int M0[5], M1[5];                     // batch slot (0..7) or 8
    int ii0[9], ii1[9], vv0[9], vv1[9];   // idx/valid ring 9 (dist 8)

    const bf16x8 zero8 = {};

    // ---- prologue: idx tiles 0..7
#pragma unroll
    for (int s = 0; s < 8; ++s) {
        const long kb = (long)s * NPTS;
        ii0[s] = __builtin_nontemporal_load(nbr_idx + kb + r0c);
        ii1[s] = __builtin_nontemporal_load(nbr_idx + kb + r1c);
        vv0[s] = __builtin_nontemporal_load(nbr_valid + kb + r0c);
        vv1[s] = __builtin_nontemporal_load(nbr_valid + kb + r1c);
    }
    // ---- prologue: gathers for tiles 0..3
#pragma unroll
    for (int s = 0; s < 4; ++s) {
        const int g0 = ii0[s], g1 = ii1[s];
        const bool va0 = vv0[s] && ok0;
        const bool va1 = vv1[s] && ok1;
        bf16x8 x0 = zero8, x1 = zero8;
        if (va0) x0 = *(const bf16x8*)(xh + (size_t)g0 * 32 + quad * 8);
        if (va1) x1 = *(const bf16x8*)(xh + (size_t)g1 * 32 + quad * 8);
        X0[s] = x0; X1[s] = x1;
        M0[s] = va0 ? batch_of(g0, t1, t2, t3, t4, t5, t6, t7) : 8;
        M1[s] = va1 ? batch_of(g1, t1, t2, t3, t4, t5, t6, t7) : 8;
    }

    const __bf16 onebf = (__bf16)1.0f;
    const __bf16 zbf   = (__bf16)0.0f;

#pragma unroll
    for (int j = 0; j < KOFF; ++j) {
        // ---- restage next 7-k chunk (three restages: j=7,14,21)
        if (j > 0 && (j % KSTAGE) == 0) {
            __syncthreads();
            stage(j);
            __syncthreads();
        }

        // ---- (P2) gathers for tile j+4 (exec-masked; vmcnt queue stays deep)
        if (j + 4 < KOFF) {
            const int s = (j + 4) % 5;
            const int si = (j + 4) % 9;
            const int g0 = ii0[si], g1 = ii1[si];
            const bool va0 = vv0[si] && ok0;
            const bool va1 = vv1[si] && ok1;
            bf16x8 x0 = zero8, x1 = zero8;
            if (va0) x0 = *(const bf16x8*)(xh + (size_t)g0 * 32 + quad * 8);
            if (va1) x1 = *(const bf16x8*)(xh + (size_t)g1 * 32 + quad * 8);
            X0[s] = x0; X1[s] = x1;
            M0[s] = va0 ? batch_of(g0, t1, t2, t3, t4, t5, t6, t7) : 8;
            M1[s] = va1 ? batch_of(g1, t1, t2, t3, t4, t5, t6, t7) : 8;
        }

        // ---- (P3) idx/valid prefetch for tile j+8
        if (j + 8 < KOFF) {
            const int si = (j + 8) % 9;
            const long kb = (long)(j + 8) * NPTS;
            ii0[si] = __builtin_nontemporal_load(nbr_idx + kb + r0c);
            ii1[si] = __builtin_nontemporal_load(nbr_idx + kb + r1c);
            vv0[si] = __builtin_nontemporal_load(nbr_valid + kb + r0c);
            vv1[si] = __builtin_nontemporal_load(nbr_valid + kb + r1c);
        }

        // ---- (P4) wf/tf from LDS (lgkmcnt only) + one-hot + MFMA
        const int kk = j % KSTAGE;
        bf16x8 wf[4];
        {
            const bf16x8* wk = (const bf16x8*)w_lds + kk * 256;
#pragma unroll
            for (int ct = 0; ct < 4; ++ct)
                wf[ct] = wk[(ct * 16 + l15) * 4 + quad];
        }
        bf16x8 tf[4];
        if (quad == 0) {
            const bf16x8* tk = (const bf16x8*)t_lds + kk * 64;
#pragma unroll
            for (int ct = 0; ct < 4; ++ct) tf[ct] = tk[ct * 16 + l15];
        } else {
#pragma unroll
            for (int ct = 0; ct < 4; ++ct) tf[ct] = zero8;
        }

        const int s = j % 5;
        const int m0 = (quad == 0) ? M0[s] : 8;
        const int m1 = (quad == 0) ? M1[s] : 8;
        bf16x8 oh0, oh1;
#pragma unroll
        for (int jj = 0; jj < 8; ++jj) {
            oh0[jj] = (m0 == jj) ? onebf : zbf;
            oh1[jj] = (m1 == jj) ? onebf : zbf;
        }
#pragma unroll
        for (int ct = 0; ct < 4; ++ct) {
            acc[0][ct] = __builtin_amdgcn_mfma_f32_16x16x32_bf16(wf[ct], X0[s], acc[0][ct], 0, 0, 0);
            acc[1][ct] = __builtin_amdgcn_mfma_f32_16x16x32_bf16(wf[ct], X1[s], acc[1][ct], 0, 0, 0);
            acc[0][ct] = __builtin_amdgcn_mfma_f32_16x16x32_bf16(tf[ct], oh0, acc[0][ct], 0, 0, 0);
            acc[1][ct] = __builtin_amdgcn_mfma_f32_16x16x32_bf16(tf[ct], oh1, acc[1][ct], 0, 0, 0);
        }
    }

    // ---- store pre-BN: lane holds couts {ct*16+quad*4..+3} of point (m, l15)
#pragma unroll
    for (int m = 0; m < 2; ++m) {
        const int p = R0 + m * 16 + l15;
        if (p < NPTS) {
            if (BF16PRE) {
                __bf16* pp = pre + (size_t)p * 64 + quad * 4;
#pragma unroll
                for (int ct = 0; ct < 4; ++ct) {
                    const f32x4 a = acc[m][ct];
                    bf16x4 o;
                    o[0] = (__bf16)a[0]; o[1] = (__bf16)a[1];
                    o[2] = (__bf16)a[2]; o[3] = (__bf16)a[3];
                    *(bf16x4*)(pp + ct * 16) = o;
                }
            } else {
                float* pp = outf + (size_t)p * 64 + quad * 4;
#pragma unroll
                for (int ct = 0; ct < 4; ++ct)
                    *(f32x4*)(pp + ct * 16) = acc[m][ct];
            }
        }
    }

    // ---- BN partials: reduce over the 16 points (l15 lanes) per cout
    const size_t pb = ((size_t)blockIdx.x * 4 + wave) * 128;
#pragma unroll
    for (int ct = 0; ct < 4; ++ct) {
        f32x4 sv, qv;
#pragma unroll
        for (int j = 0; j < 4; ++j) {
            float s  = acc[0][ct][j] + acc[1][ct][j];
            float ss = acc[0][ct][j] * acc[0][ct][j] + acc[1][ct][j] * acc[1][ct][j];
            s += __shfl_xor(s, 1);  ss += __shfl_xor(ss, 1);
            s += __shfl_xor(s, 2);  ss += __shfl_xor(ss, 2);
            s += __shfl_xor(s, 4);  ss += __shfl_xor(ss, 4);
            s += __shfl_xor(s, 8);  ss += __shfl_xor(ss, 8);
            sv[j] = s; qv[j] = ss;
        }
        if (l15 == 0) {
            *(f32x4*)(partials + pb + ct * 16 + quad * 4)      = sv;
            *(f32x4*)(partials + pb + 64 + ct * 16 + quad * 4) = qv;
        }
    }
}

// ---------------- Kernel 4: reduce partials [NWAVES][128] -> p2 [128][128]
__global__ __launch_bounds__(256) void bn_pass1(
    const float* __restrict__ partials, float* __restrict__ p2)
{
    __shared__ float lds[256];
    const int tid = threadIdx.x;
    const int c = tid & 127;
    const int half = tid >> 7;
    float s = 0.f;
    for (int r = blockIdx.x * 2 + half; r < NWAVES; r += 256)
        s += __builtin_nontemporal_load(partials + (size_t)r * 128 + c);
    lds[tid] = s;
    __syncthreads();
    if (tid < 128) p2[blockIdx.x * 128 + tid] = lds[tid] + lds[tid + 128];
}

// ---------------- Kernel 5: finalize BN scale/shift
__global__ void bn_pass2(const float* __restrict__ p2, const float* __restrict__ gamma,
                         const float* __restrict__ beta, float* __restrict__ bn)
{
    __shared__ float lds[128];
    const int t = threadIdx.x;
    float s = 0.f;
    for (int b = 0; b < 128; ++b) s += p2[b * 128 + t];
    lds[t] = s;
    __syncthreads();
    if (t < 64) {
        const float inv_n = 1.0f / (float)NPTS;
        const float mean = lds[t] * inv_n;
        const float var = lds[t + 64] * inv_n - mean * mean;
        const float scale = rsqrtf(var + 1e-5f) * gamma[t];
        bn[t] = scale;
        bn[64 + t] = beta[t] - mean * scale;   // conv bias cancels under BN; omitted
    }
}

// ---------------- Kernel 6a: y = silu(pre_bf16*scale + shift) -> f32 d_out
__global__ __launch_bounds__(256) void bn_silu_bf16_kernel(
    const __bf16* __restrict__ pre, float* __restrict__ out, const float* __restrict__ bn)
{
    __shared__ float s[128];
    if (threadIdx.x < 128) s[threadIdx.x] = bn[threadIdx.x];
    __syncthreads();
    const long M8 = (long)NPTS * 8;
    for (long i = (long)blockIdx.x * 256 + threadIdx.x; i < M8; i += (long)gridDim.x * 256) {
        const int c0 = ((int)i & 7) << 3;
        const bf16x8 v = __builtin_nontemporal_load((const bf16x8*)pre + i);
        f32x4 lo, hi;
#pragma unroll
        for (int j = 0; j < 4; ++j) {
            const float y = (float)v[j] * s[c0 + j] + s[64 + c0 + j];
            lo[j] = y * (1.0f / (1.0f + __expf(-y)));
        }
#pragma unroll
        for (int j = 0; j < 4; ++j) {
            const float y = (float)v[4 + j] * s[c0 + 4 + j] + s[64 + c0 + 4 + j];
            hi[j] = y * (1.0f / (1.0f + __expf(-y)));
        }
        f32x4* o = (f32x4*)out + i * 2;
        o[0] = lo; o[1] = hi;
    }
}

// ---------------- Kernel 6b: fallback, f32 pre-BN in-place on d_out
__global__ __launch_bounds__(256) void bn_silu_f32_kernel(
    float* __restrict__ out, const float* __restrict__ bn)
{
    __shared__ float s[128];
    if (threadIdx.x < 128) s[threadIdx.x] = bn[threadIdx.x];
    __syncthreads();
    f32x4* o4 = (f32x4*)out;
    const long M4 = (long)NPTS * 16;
    for (long i = (long)blockIdx.x * 256 + threadIdx.x; i < M4; i += (long)gridDim.x * 256) {
        const int c0 = ((int)i & 15) << 2;
        f32x4 v = __builtin_nontemporal_load(o4 + i);
#pragma unroll
        for (int j = 0; j < 4; ++j) {
            const float y = v[j] * s[c0 + j] + s[64 + c0 + j];
            v[j] = y * (1.0f / (1.0f + __expf(-y)));
        }
        o4[i] = v;
    }
}

extern "C" void kernel_launch(void* const* d_in, const int* in_sizes, int n_in,
                              void* d_out, int out_size, void* d_ws, size_t ws_size,
                              hipStream_t stream)
{
    const float* feats     = (const float*)d_in[0];
    const float* time_emb  = (const float*)d_in[1];
    const float* W         = (const float*)d_in[2];
    /* d_in[3] = bias: cancels exactly under training-mode BN -> unused */
    const float* gamma     = (const float*)d_in[4];
    const float* beta      = (const float*)d_in[5];
    const int*   batch_idx = (const int*)d_in[6];
    const int*   nbr_idx   = (const int*)d_in[7];
    const int*   nbr_valid = (const int*)d_in[8];
    float* out = (float*)d_out;

    char* ws = (char*)d_ws;
    size_t off = 0;
    auto take = [&](size_t bytes) { char* p = ws + off; off = (off + bytes + 255) & ~(size_t)255; return p; };
    __bf16* xh      = (__bf16*)take((size_t)NPTS * 32 * 2);          // 64 MB
    int* bounds     = (int*)take(9 * 4);
    __bf16* wlo     = (__bf16*)take((size_t)KOFF * 2048 * 2);        // 108 KB
    __bf16* twc     = (__bf16*)take((size_t)KOFF * 512 * 2);         // 27 KB
    float* partials = (float*)take((size_t)NWAVES * 128 * 4);        // 16 MB
    float* p2       = (float*)take(128 * 128 * 4);
    float* bn       = (float*)take(512);
    const size_t pre_bytes = (size_t)NPTS * 64 * 2;                  // 128 MB
    const bool bf16pre = (off + pre_bytes) <= ws_size;
    __bf16* pre = bf16pre ? (__bf16*)take(pre_bytes) : (__bf16*)0;

    hipLaunchKernelGGL(build_xh_kernel, dim3(31250), dim3(256), 0, stream, feats, xh);
    hipLaunchKernelGGL(prep_kernel, dim3(271), dim3(256), 0, stream,
                       W, time_emb, batch_idx, wlo, twc, bounds);
    if (bf16pre) {
        hipLaunchKernelGGL((conv_kernel<1>), dim3(NWG_CONV), dim3(CONV_BLOCK), 0, stream,
                           xh, bounds, wlo, twc, nbr_idx, nbr_valid, out, pre, partials);
    } else {
        hipLaunchKernelGGL((conv_kernel<0>), dim3(NWG_CONV), dim3(CONV_BLOCK), 0, stream,
                           xh, bounds, wlo, twc, nbr_idx, nbr_valid, out, pre, partials);
    }
    hipLaunchKernelGGL(bn_pass1, dim3(128), dim3(256), 0, stream, partials, p2);
    hipLaunchKernelGGL(bn_pass2, dim3(1), dim3(128), 0, stream, p2, gamma, beta, bn);
    if (bf16pre) {
        hipLaunchKernelGGL(bn_silu_bf16_kernel, dim3(2048), dim3(256), 0, stream, pre, out, bn);
    } else {
        hipLaunchKernelGGL(bn_silu_f32_kernel, dim3(2048), dim3(256), 0, stream, out, bn);
    }
}

// Round 14
// 579.699 us; speedup vs baseline: 1.0038x; 1.0038x over previous
//
#include <hip/hip_runtime.h>

#define NPTS 1000000
#define KOFF 27
#define KSTAGE 9                  // 3 LDS stages of 9 k-offsets (r12 proven: 3 blocks/CU)
#define GDIST 6                   // gather issue distance
#define IDIST 12                  // idx issue distance = 2*GDIST (vmcnt alignment law)
#define XRING 7                   // GDIST+1
#define IRING 13                  // IDIST+1
#define CONV_BLOCK 256
#define ROWS_PER_BLOCK 128        // 4 waves x 32 rows
#define NWG_CONV 7813             // ceil(1e6/128)
#define NWAVES (NWG_CONV * 4)

typedef __bf16 bf16x8 __attribute__((ext_vector_type(8)));
typedef __bf16 bf16x4 __attribute__((ext_vector_type(4)));
typedef float f32x4 __attribute__((ext_vector_type(4)));

// ---------------- Kernel 1: xh[N][32] = bf16(feats)  (the ONLY gather target, 64 MB)
__global__ __launch_bounds__(256) void build_xh_kernel(
    const float* __restrict__ feats, __bf16* __restrict__ xh)
{
    const long g = (long)blockIdx.x * 256 + threadIdx.x;
    if (g >= (long)NPTS * 8) return;
    const int row = (int)(g >> 3);
    const int c = ((int)g & 7) << 2;
    f32x4 v = __builtin_nontemporal_load((const f32x4*)(feats + (size_t)row * 32 + c));
    bf16x4 o;
    o[0] = (__bf16)v[0]; o[1] = (__bf16)v[1];
    o[2] = (__bf16)v[2]; o[3] = (__bf16)v[3];
    *(bf16x4*)(xh + (size_t)row * 32 + c) = o;
}

// ---------------- Kernel 2 (merged prep): wlo / twc(compact 8-slot) / bounds
__global__ __launch_bounds__(256) void prep_kernel(
    const float* __restrict__ W, const float* __restrict__ time_emb,
    const int* __restrict__ batch_idx,
    __bf16* __restrict__ wlo, __bf16* __restrict__ twc, int* __restrict__ bounds)
{
    const int b = blockIdx.x;
    if (b < 216) {
        // wlo[k][cout][cin0..31]
        const int g = b * 256 + threadIdx.x;
        const int k = g >> 11, rem = g & 2047;
        const int co = rem >> 5, ci = rem & 31;
        wlo[g] = (__bf16)W[k * 4096 + ci * 64 + co];
    } else if (b < 270) {
        // twc[k][cout][slot0..7] = time_emb[slot]·W[k][32:,cout]
        const int g = (b - 216) * 256 + threadIdx.x;
        if (g >= KOFF * 512) return;
        const int k = g >> 9, rem = g & 511;
        const int co = rem >> 3, slot = rem & 7;
        float v = 0.f;
#pragma unroll
        for (int ci = 0; ci < 32; ++ci)
            v += time_emb[slot * 32 + ci] * W[k * 4096 + (32 + ci) * 64 + co];
        twc[g] = (__bf16)v;
    } else {
        const int j = threadIdx.x;
        if (j > 8) return;
        if (j == 0) { bounds[0] = 0; return; }
        if (j == 8) { bounds[8] = NPTS; return; }
        int lo = 0, hi = NPTS;
        while (lo < hi) {
            const int mid = (lo + hi) >> 1;
            if (batch_idx[mid] < j) lo = mid + 1; else hi = mid;
        }
        bounds[j] = lo;
    }
}

__device__ __forceinline__ int batch_of(int g, int t1, int t2, int t3, int t4,
                                        int t5, int t6, int t7)
{
    return (g >= t1) + (g >= t2) + (g >= t3) + (g >= t4) +
           (g >= t5) + (g >= t6) + (g >= t7);
}

// ---------------- Kernel 3: gather-GEMM conv.
// r14 = r12 (KSTAGE=9, 256-thread, 3 blocks/CU proven) + DEEPER gather pipeline:
// gather dist 6, idx dist 12. Alignment law: idx_dist = 2*gather_dist so the
// in-order vmcnt wait on idx[j+GDIST] retires exactly gather[j] — the tile P4
// needs this iteration anyway. Outstanding gather-instr/CU: 96 -> 144.
// All weight/tw reads are LDS (lgkmcnt: never drains the vmcnt gather queue).
template <int BF16PRE>
__global__ __launch_bounds__(CONV_BLOCK, 2) void conv_kernel(
    const __bf16* __restrict__ xh, const int* __restrict__ bounds,
    const __bf16* __restrict__ wlo, const __bf16* __restrict__ twc,
    const int* __restrict__ nbr_idx, const int* __restrict__ nbr_valid,
    float* __restrict__ outf, __bf16* __restrict__ pre,
    float* __restrict__ partials)
{
    __shared__ __bf16 w_lds[KSTAGE * 2048];   // 36 KB: [kk][cout][cin0..31]
    __shared__ __bf16 t_lds[KSTAGE * 512];    // 9 KB:  [kk][cout][slot0..7]

    const int tid  = threadIdx.x;
    const int wave = tid >> 6;
    const int lane = tid & 63;
    const int l15  = lane & 15;
    const int quad = lane >> 4;
    const int R0   = blockIdx.x * ROWS_PER_BLOCK + wave * 32;
    const int row0 = R0 + l15;
    const int row1 = row0 + 16;
    const bool ok0 = row0 < NPTS;
    const bool ok1 = row1 < NPTS;
    const int r0c = ok0 ? row0 : NPTS - 1;
    const int r1c = ok1 ? row1 : NPTS - 1;

    auto stage = [&](int k0) {
        const bf16x8* wsrc = (const bf16x8*)wlo + (size_t)k0 * 256;
        bf16x8* wdst = (bf16x8*)w_lds;
#pragma unroll
        for (int i = 0; i < 9; ++i) {             // 2304 chunks / 256 threads
            const int c = tid + i * CONV_BLOCK;
            if (c < KSTAGE * 256) wdst[c] = wsrc[c];
        }
        const bf16x8* tsrc = (const bf16x8*)twc + (size_t)k0 * 64;
        bf16x8* tdst = (bf16x8*)t_lds;
#pragma unroll
        for (int i = 0; i < 3; ++i) {             // 576 chunks / 256 threads
            const int c = tid + i * CONV_BLOCK;
            if (c < KSTAGE * 64) tdst[c] = tsrc[c];
        }
    };

    stage(0);
    __syncthreads();

    const int t1 = __builtin_amdgcn_readfirstlane(bounds[1]);
    const int t2 = __builtin_amdgcn_readfirstlane(bounds[2]);
    const int t3 = __builtin_amdgcn_readfirstlane(bounds[3]);
    const int t4 = __builtin_amdgcn_readfirstlane(bounds[4]);
    const int t5 = __builtin_amdgcn_readfirstlane(bounds[5]);
    const int t6 = __builtin_amdgcn_readfirstlane(bounds[6]);
    const int t7 = __builtin_amdgcn_readfirstlane(bounds[7]);

    f32x4 acc[2][4];
#pragma unroll
    for (int m = 0; m < 2; ++m)
#pragma unroll
        for (int ct = 0; ct < 4; ++ct)
            acc[m][ct] = (f32x4){0.f, 0.f, 0.f, 0.f};

    bf16x8 X0[XRING], X1[XRING];          // gathered feat fragments (dist 6)
    int M0[XRING], M1[XRING];             // batch slot (0..7) or 8
    int ii0[IRING], ii1[IRING], vv0[IRING], vv1[IRING];   // idx/valid (dist 12)

    const bf16x8 zero8 = {};

    // ---- prologue: idx tiles 0..11
#pragma unroll
    for (int s = 0; s < IDIST; ++s) {
        const long kb = (long)s * NPTS;
        ii0[s] = __builtin_nontemporal_load(nbr_idx + kb + r0c);
        ii1[s] = __builtin_nontemporal_load(nbr_idx + kb + r1c);
        vv0[s] = __builtin_nontemporal_load(nbr_valid + kb + r0c);
        vv1[s] = __builtin_nontemporal_load(nbr_valid + kb + r1c);
    }
    // ---- prologue: gathers for tiles 0..5
#pragma unroll
    for (int s = 0; s < GDIST; ++s) {
        const int g0 = ii0[s], g1 = ii1[s];
        const bool va0 = vv0[s] && ok0;
        const bool va1 = vv1[s] && ok1;
        bf16x8 x0 = zero8, x1 = zero8;
        if (va0) x0 = *(const bf16x8*)(xh + (size_t)g0 * 32 + quad * 8);
        if (va1) x1 = *(const bf16x8*)(xh + (size_t)g1 * 32 + quad * 8);
        X0[s] = x0; X1[s] = x1;
        M0[s] = va0 ? batch_of(g0, t1, t2, t3, t4, t5, t6, t7) : 8;
        M1[s] = va1 ? batch_of(g1, t1, t2, t3, t4, t5, t6, t7) : 8;
    }

    const __bf16 onebf = (__bf16)1.0f;
    const __bf16 zbf   = (__bf16)0.0f;

#pragma unroll
    for (int j = 0; j < KOFF; ++j) {
        // ---- restage next 9-k chunk (two restages: j=9,18)
        if (j == KSTAGE || j == 2 * KSTAGE) {
            __syncthreads();
            stage(j);
            __syncthreads();
        }

        // ---- (P2) gathers for tile j+6 (exec-masked; aligned idx retirement)
        if (j + GDIST < KOFF) {
            const int s = (j + GDIST) % XRING;
            const int si = (j + GDIST) % IRING;
            const int g0 = ii0[si], g1 = ii1[si];
            const bool va0 = vv0[si] && ok0;
            const bool va1 = vv1[si] && ok1;
            bf16x8 x0 = zero8, x1 = zero8;
            if (va0) x0 = *(const bf16x8*)(xh + (size_t)g0 * 32 + quad * 8);
            if (va1) x1 = *(const bf16x8*)(xh + (size_t)g1 * 32 + quad * 8);
            X0[s] = x0; X1[s] = x1;
            M0[s] = va0 ? batch_of(g0, t1, t2, t3, t4, t5, t6, t7) : 8;
            M1[s] = va1 ? batch_of(g1, t1, t2, t3, t4, t5, t6, t7) : 8;
        }

        // ---- (P3) idx/valid prefetch for tile j+12
        if (j + IDIST < KOFF) {
            const int si = (j + IDIST) % IRING;
            const long kb = (long)(j + IDIST) * NPTS;
            ii0[si] = __builtin_nontemporal_load(nbr_idx + kb + r0c);
            ii1[si] = __builtin_nontemporal_load(nbr_idx + kb + r1c);
            vv0[si] = __builtin_nontemporal_load(nbr_valid + kb + r0c);
            vv1[si] = __builtin_nontemporal_load(nbr_valid + kb + r1c);
        }

        // ---- (P4) wf/tf from LDS (lgkmcnt only) + one-hot + MFMA
        const int kk = j % KSTAGE;
        bf16x8 wf[4];
        {
            const bf16x8* wk = (const bf16x8*)w_lds + kk * 256;
#pragma unroll
            for (int ct = 0; ct < 4; ++ct)
                wf[ct] = wk[(ct * 16 + l15) * 4 + quad];
        }
        bf16x8 tf[4];
        if (quad == 0) {
            const bf16x8* tk = (const bf16x8*)t_lds + kk * 64;
#pragma unroll
            for (int ct = 0; ct < 4; ++ct) tf[ct] = tk[ct * 16 + l15];
        } else {
#pragma unroll
            for (int ct = 0; ct < 4; ++ct) tf[ct] = zero8;
        }

        const int s = j % XRING;
        const int m0 = (quad == 0) ? M0[s] : 8;
        const int m1 = (quad == 0) ? M1[s] : 8;
        bf16x8 oh0, oh1;
#pragma unroll
        for (int jj = 0; jj < 8; ++jj) {
            oh0[jj] = (m0 == jj) ? onebf : zbf;
            oh1[jj] = (m1 == jj) ? onebf : zbf;
        }
#pragma unroll
        for (int ct = 0; ct < 4; ++ct) {
            acc[0][ct] = __builtin_amdgcn_mfma_f32_16x16x32_bf16(wf[ct], X0[s], acc[0][ct], 0, 0, 0);
            acc[1][ct] = __builtin_amdgcn_mfma_f32_16x16x32_bf16(wf[ct], X1[s], acc[1][ct], 0, 0, 0);
            acc[0][ct] = __builtin_amdgcn_mfma_f32_16x16x32_bf16(tf[ct], oh0, acc[0][ct], 0, 0, 0);
            acc[1][ct] = __builtin_amdgcn_mfma_f32_16x16x32_bf16(tf[ct], oh1, acc[1][ct], 0, 0, 0);
        }
    }

    // ---- store pre-BN: lane holds couts {ct*16+quad*4..+3} of point (m, l15)
#pragma unroll
    for (int m = 0; m < 2; ++m) {
        const int p = R0 + m * 16 + l15;
        if (p < NPTS) {
            if (BF16PRE) {
                __bf16* pp = pre + (size_t)p * 64 + quad * 4;
#pragma unroll
                for (int ct = 0; ct < 4; ++ct) {
                    const f32x4 a = acc[m][ct];
                    bf16x4 o;
                    o[0] = (__bf16)a[0]; o[1] = (__bf16)a[1];
                    o[2] = (__bf16)a[2]; o[3] = (__bf16)a[3];
                    *(bf16x4*)(pp + ct * 16) = o;
                }
            } else {
                float* pp = outf + (size_t)p * 64 + quad * 4;
#pragma unroll
                for (int ct = 0; ct < 4; ++ct)
                    *(f32x4*)(pp + ct * 16) = acc[m][ct];
            }
        }
    }

    // ---- BN partials: reduce over the 16 points (l15 lanes) per cout
    const size_t pb = ((size_t)blockIdx.x * 4 + wave) * 128;
#pragma unroll
    for (int ct = 0; ct < 4; ++ct) {
        f32x4 sv, qv;
#pragma unroll
        for (int j = 0; j < 4; ++j) {
            float s  = acc[0][ct][j] + acc[1][ct][j];
            float ss = acc[0][ct][j] * acc[0][ct][j] + acc[1][ct][j] * acc[1][ct][j];
            s += __shfl_xor(s, 1);  ss += __shfl_xor(ss, 1);
            s += __shfl_xor(s, 2);  ss += __shfl_xor(ss, 2);
            s += __shfl_xor(s, 4);  ss += __shfl_xor(ss, 4);
            s += __shfl_xor(s, 8);  ss += __shfl_xor(ss, 8);
            sv[j] = s; qv[j] = ss;
        }
        if (l15 == 0) {
            *(f32x4*)(partials + pb + ct * 16 + quad * 4)      = sv;
            *(f32x4*)(partials + pb + 64 + ct * 16 + quad * 4) = qv;
        }
    }
}

// ---------------- Kernel 4: reduce partials [NWAVES][128] -> p2 [128][128]
__global__ __launch_bounds__(256) void bn_pass1(
    const float* __restrict__ partials, float* __restrict__ p2)
{
    __shared__ float lds[256];
    const int tid = threadIdx.x;
    const int c = tid & 127;
    const int half = tid >> 7;
    float s = 0.f;
    for (int r = blockIdx.x * 2 + half; r < NWAVES; r += 256)
        s += __builtin_nontemporal_load(partials + (size_t)r * 128 + c);
    lds[tid] = s;
    __syncthreads();
    if (tid < 128) p2[blockIdx.x * 128 + tid] = lds[tid] + lds[tid + 128];
}

// ---------------- Kernel 5: finalize BN scale/shift
__global__ void bn_pass2(const float* __restrict__ p2, const float* __restrict__ gamma,
                         const float* __restrict__ beta, float* __restrict__ bn)
{
    __shared__ float lds[128];
    const int t = threadIdx.x;
    float s = 0.f;
    for (int b = 0; b < 128; ++b) s += p2[b * 128 + t];
    lds[t] = s;
    __syncthreads();
    if (t < 64) {
        const float inv_n = 1.0f / (float)NPTS;
        const float mean = lds[t] * inv_n;
        const float var = lds[t + 64] * inv_n - mean * mean;
        const float scale = rsqrtf(var + 1e-5f) * gamma[t];
        bn[t] = scale;
        bn[64 + t] = beta[t] - mean * scale;   // conv bias cancels under BN; omitted
    }
}

// ---------------- Kernel 6a: y = silu(pre_bf16*scale + shift) -> f32 d_out
__global__ __launch_bounds__(256) void bn_silu_bf16_kernel(
    const __bf16* __restrict__ pre, float* __restrict__ out, const float* __restrict__ bn)
{
    __shared__ float s[128];
    if (threadIdx.x < 128) s[threadIdx.x] = bn[threadIdx.x];
    __syncthreads();
    const long M8 = (long)NPTS * 8;
    for (long i = (long)blockIdx.x * 256 + threadIdx.x; i < M8; i += (long)gridDim.x * 256) {
        const int c0 = ((int)i & 7) << 3;
        const bf16x8 v = __builtin_nontemporal_load((const bf16x8*)pre + i);
        f32x4 lo, hi;
#pragma unroll
        for (int j = 0; j < 4; ++j) {
            const float y = (float)v[j] * s[c0 + j] + s[64 + c0 + j];
            lo[j] = y * (1.0f / (1.0f + __expf(-y)));
        }
#pragma unroll
        for (int j = 0; j < 4; ++j) {
            const float y = (float)v[4 + j] * s[c0 + 4 + j] + s[64 + c0 + 4 + j];
            hi[j] = y * (1.0f / (1.0f + __expf(-y)));
        }
        f32x4* o = (f32x4*)out + i * 2;
        o[0] = lo; o[1] = hi;
    }
}

// ---------------- Kernel 6b: fallback, f32 pre-BN in-place on d_out
__global__ __launch_bounds__(256) void bn_silu_f32_kernel(
    float* __restrict__ out, const float* __restrict__ bn)
{
    __shared__ float s[128];
    if (threadIdx.x < 128) s[threadIdx.x] = bn[threadIdx.x];
    __syncthreads();
    f32x4* o4 = (f32x4*)out;
    const long M4 = (long)NPTS * 16;
    for (long i = (long)blockIdx.x * 256 + threadIdx.x; i < M4; i += (long)gridDim.x * 256) {
        const int c0 = ((int)i & 15) << 2;
        f32x4 v = __builtin_nontemporal_load(o4 + i);
#pragma unroll
        for (int j = 0; j < 4; ++j) {
            const float y = v[j] * s[c0 + j] + s[64 + c0 + j];
            v[j] = y * (1.0f / (1.0f + __expf(-y)));
        }
        o4[i] = v;
    }
}

extern "C" void kernel_launch(void* const* d_in, const int* in_sizes, int n_in,
                              void* d_out, int out_size, void* d_ws, size_t ws_size,
                              hipStream_t stream)
{
    const float* feats     = (const float*)d_in[0];
    const float* time_emb  = (const float*)d_in[1];
    const float* W         = (const float*)d_in[2];
    /* d_in[3] = bias: cancels exactly under training-mode BN -> unused */
    const float* gamma     = (const float*)d_in[4];
    const float* beta      = (const float*)d_in[5];
    const int*   batch_idx = (const int*)d_in[6];
    const int*   nbr_idx   = (const int*)d_in[7];
    const int*   nbr_valid = (const int*)d_in[8];
    float* out = (float*)d_out;

    char* ws = (char*)d_ws;
    size_t off = 0;
    auto take = [&](size_t bytes) { char* p = ws + off; off = (off + bytes + 255) & ~(size_t)255; return p; };
    __bf16* xh      = (__bf16*)take((size_t)NPTS * 32 * 2);          // 64 MB
    int* bounds     = (int*)take(9 * 4);
    __bf16* wlo     = (__bf16*)take((size_t)KOFF * 2048 * 2);        // 108 KB
    __bf16* twc     = (__bf16*)take((size_t)KOFF * 512 * 2);         // 27 KB
    float* partials = (float*)take((size_t)NWAVES * 128 * 4);        // 16 MB
    float* p2       = (float*)take(128 * 128 * 4);
    float* bn       = (float*)take(512);
    const size_t pre_bytes = (size_t)NPTS * 64 * 2;                  // 128 MB
    const bool bf16pre = (off + pre_bytes) <= ws_size;
    __bf16* pre = bf16pre ? (__bf16*)take(pre_bytes) : (__bf16*)0;

    hipLaunchKernelGGL(build_xh_kernel, dim3(31250), dim3(256), 0, stream, feats, xh);
    hipLaunchKernelGGL(prep_kernel, dim3(271), dim3(256), 0, stream,
                       W, time_emb, batch_idx, wlo, twc, bounds);
    if (bf16pre) {
        hipLaunchKernelGGL((conv_kernel<1>), dim3(NWG_CONV), dim3(CONV_BLOCK), 0, stream,
                           xh, bounds, wlo, twc, nbr_idx, nbr_valid, out, pre, partials);
    } else {
        hipLaunchKernelGGL((conv_kernel<0>), dim3(NWG_CONV), dim3(CONV_BLOCK), 0, stream,
                           xh, bounds, wlo, twc, nbr_idx, nbr_valid, out, pre, partials);
    }
    hipLaunchKernelGGL(bn_pass1, dim3(128), dim3(256), 0, stream, partials, p2);
    hipLaunchKernelGGL(bn_pass2, dim3(1), dim3(128), 0, stream, p2, gamma, beta, bn);
    if (bf16pre) {
        hipLaunchKernelGGL(bn_silu_bf16_kernel, dim3(2048), dim3(256), 0, stream, pre, out, bn);
    } else {
        hipLaunchKernelGGL(bn_silu_f32_kernel, dim3(2048), dim3(256), 0, stream, out, bn);
    }
}

// Round 15
// 500.444 us; speedup vs baseline: 1.1628x; 1.1584x over previous
//
#include <hip/hip_runtime.h>

#define NPTS 1000000
#define KOFF 27
#define KSTAGE 9                  // 3 LDS stages of 9 k-offsets -> 45 KB/block, 3 blocks/CU (proven r12)
#define CONV_BLOCK 256
#define ROWS_PER_BLOCK 128        // 4 waves x 32 rows
#define NWG_CONV 7813             // ceil(1e6/128)
#define NWAVES (NWG_CONV * 4)

typedef __bf16 bf16x8 __attribute__((ext_vector_type(8)));
typedef __bf16 bf16x4 __attribute__((ext_vector_type(4)));
typedef float f32x4 __attribute__((ext_vector_type(4)));

// ---------------- Kernel 1: xh[N][32] = bf16(feats)  (the ONLY gather target, 64 MB)
__global__ __launch_bounds__(256) void build_xh_kernel(
    const float* __restrict__ feats, __bf16* __restrict__ xh)
{
    const long g = (long)blockIdx.x * 256 + threadIdx.x;
    if (g >= (long)NPTS * 8) return;
    const int row = (int)(g >> 3);
    const int c = ((int)g & 7) << 2;
    f32x4 v = __builtin_nontemporal_load((const f32x4*)(feats + (size_t)row * 32 + c));
    bf16x4 o;
    o[0] = (__bf16)v[0]; o[1] = (__bf16)v[1];
    o[2] = (__bf16)v[2]; o[3] = (__bf16)v[3];
    *(bf16x4*)(xh + (size_t)row * 32 + c) = o;
}

// ---------------- Kernel 2 (merged prep): wlo / twc(compact 8-slot) / bounds
__global__ __launch_bounds__(256) void prep_kernel(
    const float* __restrict__ W, const float* __restrict__ time_emb,
    const int* __restrict__ batch_idx,
    __bf16* __restrict__ wlo, __bf16* __restrict__ twc, int* __restrict__ bounds)
{
    const int b = blockIdx.x;
    if (b < 216) {
        // wlo[k][cout][cin0..31]
        const int g = b * 256 + threadIdx.x;
        const int k = g >> 11, rem = g & 2047;
        const int co = rem >> 5, ci = rem & 31;
        wlo[g] = (__bf16)W[k * 4096 + ci * 64 + co];
    } else if (b < 270) {
        // twc[k][cout][slot0..7] = time_emb[slot]·W[k][32:,cout]
        const int g = (b - 216) * 256 + threadIdx.x;
        if (g >= KOFF * 512) return;
        const int k = g >> 9, rem = g & 511;
        const int co = rem >> 3, slot = rem & 7;
        float v = 0.f;
#pragma unroll
        for (int ci = 0; ci < 32; ++ci)
            v += time_emb[slot * 32 + ci] * W[k * 4096 + (32 + ci) * 64 + co];
        twc[g] = (__bf16)v;
    } else {
        const int j = threadIdx.x;
        if (j > 8) return;
        if (j == 0) { bounds[0] = 0; return; }
        if (j == 8) { bounds[8] = NPTS; return; }
        int lo = 0, hi = NPTS;
        while (lo < hi) {
            const int mid = (lo + hi) >> 1;
            if (batch_idx[mid] < j) lo = mid + 1; else hi = mid;
        }
        bounds[j] = lo;
    }
}

__device__ __forceinline__ int batch_of(int g, int t1, int t2, int t3, int t4,
                                        int t5, int t6, int t7)
{
    return (g >= t1) + (g >= t2) + (g >= t3) + (g >= t4) +
           (g >= t5) + (g >= t6) + (g >= t7);
}

// ---------------- Kernel 3: gather-GEMM conv (r12 configuration, best measured).
// 256-thread blocks, KSTAGE=9 (45 KB LDS) -> 3 blocks/CU = 12 waves (proven max).
// All weight/tw reads are LDS (lgkmcnt: never drains the vmcnt gather queue).
// X gather ring dist 4 (8 gather-instr in flight/wave), idx ring dist 8
// (= 2x gather dist: consuming idx[j+4] retires exactly gather[j], needed now).
template <int BF16PRE>
__global__ __launch_bounds__(CONV_BLOCK, 2) void conv_kernel(
    const __bf16* __restrict__ xh, const int* __restrict__ bounds,
    const __bf16* __restrict__ wlo, const __bf16* __restrict__ twc,
    const int* __restrict__ nbr_idx, const int* __restrict__ nbr_valid,
    float* __restrict__ outf, __bf16* __restrict__ pre,
    float* __restrict__ partials)
{
    __shared__ __bf16 w_lds[KSTAGE * 2048];   // 36 KB: [kk][cout][cin0..31]
    __shared__ __bf16 t_lds[KSTAGE * 512];    // 9 KB:  [kk][cout][slot0..7]

    const int tid  = threadIdx.x;
    const int wave = tid >> 6;
    const int lane = tid & 63;
    const int l15  = lane & 15;
    const int quad = lane >> 4;
    const int R0   = blockIdx.x * ROWS_PER_BLOCK + wave * 32;
    const int row0 = R0 + l15;
    const int row1 = row0 + 16;
    const bool ok0 = row0 < NPTS;
    const bool ok1 = row1 < NPTS;
    const int r0c = ok0 ? row0 : NPTS - 1;
    const int r1c = ok1 ? row1 : NPTS - 1;

    auto stage = [&](int k0) {
        const bf16x8* wsrc = (const bf16x8*)wlo + (size_t)k0 * 256;
        bf16x8* wdst = (bf16x8*)w_lds;
#pragma unroll
        for (int i = 0; i < 9; ++i) {             // 2304 chunks / 256 threads
            const int c = tid + i * CONV_BLOCK;
            if (c < KSTAGE * 256) wdst[c] = wsrc[c];
        }
        const bf16x8* tsrc = (const bf16x8*)twc + (size_t)k0 * 64;
        bf16x8* tdst = (bf16x8*)t_lds;
#pragma unroll
        for (int i = 0; i < 3; ++i) {             // 576 chunks / 256 threads
            const int c = tid + i * CONV_BLOCK;
            if (c < KSTAGE * 64) tdst[c] = tsrc[c];
        }
    };

    stage(0);
    __syncthreads();

    const int t1 = __builtin_amdgcn_readfirstlane(bounds[1]);
    const int t2 = __builtin_amdgcn_readfirstlane(bounds[2]);
    const int t3 = __builtin_amdgcn_readfirstlane(bounds[3]);
    const int t4 = __builtin_amdgcn_readfirstlane(bounds[4]);
    const int t5 = __builtin_amdgcn_readfirstlane(bounds[5]);
    const int t6 = __builtin_amdgcn_readfirstlane(bounds[6]);
    const int t7 = __builtin_amdgcn_readfirstlane(bounds[7]);

    f32x4 acc[2][4];
#pragma unroll
    for (int m = 0; m < 2; ++m)
#pragma unroll
        for (int ct = 0; ct < 4; ++ct)
            acc[m][ct] = (f32x4){0.f, 0.f, 0.f, 0.f};

    bf16x8 X0[5], X1[5];                  // gathered feat fragments, ring 5 (dist 4)
    int M0[5], M1[5];                     // batch slot (0..7) or 8
    int ii0[9], ii1[9], vv0[9], vv1[9];   // idx/valid stream ring 9 (dist 8)

    const bf16x8 zero8 = {};

    // ---- prologue: idx tiles 0..7
#pragma unroll
    for (int s = 0; s < 8; ++s) {
        const long kb = (long)s * NPTS;
        ii0[s] = __builtin_nontemporal_load(nbr_idx + kb + r0c);
        ii1[s] = __builtin_nontemporal_load(nbr_idx + kb + r1c);
        vv0[s] = __builtin_nontemporal_load(nbr_valid + kb + r0c);
        vv1[s] = __builtin_nontemporal_load(nbr_valid + kb + r1c);
    }
    // ---- prologue: gathers for tiles 0..3
#pragma unroll
    for (int s = 0; s < 4; ++s) {
        const int g0 = ii0[s], g1 = ii1[s];
        const bool va0 = vv0[s] && ok0;
        const bool va1 = vv1[s] && ok1;
        bf16x8 x0 = zero8, x1 = zero8;
        if (va0) x0 = *(const bf16x8*)(xh + (size_t)g0 * 32 + quad * 8);
        if (va1) x1 = *(const bf16x8*)(xh + (size_t)g1 * 32 + quad * 8);
        X0[s] = x0; X1[s] = x1;
        M0[s] = va0 ? batch_of(g0, t1, t2, t3, t4, t5, t6, t7) : 8;
        M1[s] = va1 ? batch_of(g1, t1, t2, t3, t4, t5, t6, t7) : 8;
    }

    const __bf16 onebf = (__bf16)1.0f;
    const __bf16 zbf   = (__bf16)0.0f;

#pragma unroll
    for (int j = 0; j < KOFF; ++j) {
        // ---- restage next 9-k chunk (two restages: j=9,18)
        if (j == KSTAGE || j == 2 * KSTAGE) {
            __syncthreads();
            stage(j);
            __syncthreads();
        }

        // ---- (P2) gathers for tile j+4 (exec-masked; vmcnt queue stays deep)
        if (j + 4 < KOFF) {
            const int s = (j + 4) % 5;
            const int si = (j + 4) % 9;
            const int g0 = ii0[si], g1 = ii1[si];
            const bool va0 = vv0[si] && ok0;
            const bool va1 = vv1[si] && ok1;
            bf16x8 x0 = zero8, x1 = zero8;
            if (va0) x0 = *(const bf16x8*)(xh + (size_t)g0 * 32 + quad * 8);
            if (va1) x1 = *(const bf16x8*)(xh + (size_t)g1 * 32 + quad * 8);
            X0[s] = x0; X1[s] = x1;
            M0[s] = va0 ? batch_of(g0, t1, t2, t3, t4, t5, t6, t7) : 8;
            M1[s] = va1 ? batch_of(g1, t1, t2, t3, t4, t5, t6, t7) : 8;
        }

        // ---- (P3) idx/valid prefetch for tile j+8
        if (j + 8 < KOFF) {
            const int si = (j + 8) % 9;
            const long kb = (long)(j + 8) * NPTS;
            ii0[si] = __builtin_nontemporal_load(nbr_idx + kb + r0c);
            ii1[si] = __builtin_nontemporal_load(nbr_idx + kb + r1c);
            vv0[si] = __builtin_nontemporal_load(nbr_valid + kb + r0c);
            vv1[si] = __builtin_nontemporal_load(nbr_valid + kb + r1c);
        }

        // ---- (P4) wf/tf from LDS (lgkmcnt only) + one-hot + MFMA
        const int kk = j % KSTAGE;
        bf16x8 wf[4];
        {
            const bf16x8* wk = (const bf16x8*)w_lds + kk * 256;
#pragma unroll
            for (int ct = 0; ct < 4; ++ct)
                wf[ct] = wk[(ct * 16 + l15) * 4 + quad];
        }
        bf16x8 tf[4];
        if (quad == 0) {
            const bf16x8* tk = (const bf16x8*)t_lds + kk * 64;
#pragma unroll
            for (int ct = 0; ct < 4; ++ct) tf[ct] = tk[ct * 16 + l15];
        } else {
#pragma unroll
            for (int ct = 0; ct < 4; ++ct) tf[ct] = zero8;
        }

        const int s = j % 5;
        const int m0 = (quad == 0) ? M0[s] : 8;
        const int m1 = (quad == 0) ? M1[s] : 8;
        bf16x8 oh0, oh1;
#pragma unroll
        for (int jj = 0; jj < 8; ++jj) {
            oh0[jj] = (m0 == jj) ? onebf : zbf;
            oh1[jj] = (m1 == jj) ? onebf : zbf;
        }
#pragma unroll
        for (int ct = 0; ct < 4; ++ct) {
            acc[0][ct] = __builtin_amdgcn_mfma_f32_16x16x32_bf16(wf[ct], X0[s], acc[0][ct], 0, 0, 0);
            acc[1][ct] = __builtin_amdgcn_mfma_f32_16x16x32_bf16(wf[ct], X1[s], acc[1][ct], 0, 0, 0);
            acc[0][ct] = __builtin_amdgcn_mfma_f32_16x16x32_bf16(tf[ct], oh0, acc[0][ct], 0, 0, 0);
            acc[1][ct] = __builtin_amdgcn_mfma_f32_16x16x32_bf16(tf[ct], oh1, acc[1][ct], 0, 0, 0);
        }
    }

    // ---- store pre-BN: lane holds couts {ct*16+quad*4..+3} of point (m, l15)
#pragma unroll
    for (int m = 0; m < 2; ++m) {
        const int p = R0 + m * 16 + l15;
        if (p < NPTS) {
            if (BF16PRE) {
                __bf16* pp = pre + (size_t)p * 64 + quad * 4;
#pragma unroll
                for (int ct = 0; ct < 4; ++ct) {
                    const f32x4 a = acc[m][ct];
                    bf16x4 o;
                    o[0] = (__bf16)a[0]; o[1] = (__bf16)a[1];
                    o[2] = (__bf16)a[2]; o[3] = (__bf16)a[3];
                    *(bf16x4*)(pp + ct * 16) = o;
                }
            } else {
                float* pp = outf + (size_t)p * 64 + quad * 4;
#pragma unroll
                for (int ct = 0; ct < 4; ++ct)
                    *(f32x4*)(pp + ct * 16) = acc[m][ct];
            }
        }
    }

    // ---- BN partials: reduce over the 16 points (l15 lanes) per cout
    const size_t pb = ((size_t)blockIdx.x * 4 + wave) * 128;
#pragma unroll
    for (int ct = 0; ct < 4; ++ct) {
        f32x4 sv, qv;
#pragma unroll
        for (int j = 0; j < 4; ++j) {
            float s  = acc[0][ct][j] + acc[1][ct][j];
            float ss = acc[0][ct][j] * acc[0][ct][j] + acc[1][ct][j] * acc[1][ct][j];
            s += __shfl_xor(s, 1);  ss += __shfl_xor(ss, 1);
            s += __shfl_xor(s, 2);  ss += __shfl_xor(ss, 2);
            s += __shfl_xor(s, 4);  ss += __shfl_xor(ss, 4);
            s += __shfl_xor(s, 8);  ss += __shfl_xor(ss, 8);
            sv[j] = s; qv[j] = ss;
        }
        if (l15 == 0) {
            *(f32x4*)(partials + pb + ct * 16 + quad * 4)      = sv;
            *(f32x4*)(partials + pb + 64 + ct * 16 + quad * 4) = qv;
        }
    }
}

// ---------------- Kernel 4: reduce partials [NWAVES][128] -> p2 [128][128]
__global__ __launch_bounds__(256) void bn_pass1(
    const float* __restrict__ partials, float* __restrict__ p2)
{
    __shared__ float lds[256];
    const int tid = threadIdx.x;
    const int c = tid & 127;
    const int half = tid >> 7;
    float s = 0.f;
    for (int r = blockIdx.x * 2 + half; r < NWAVES; r += 256)
        s += __builtin_nontemporal_load(partials + (size_t)r * 128 + c);
    lds[tid] = s;
    __syncthreads();
    if (tid < 128) p2[blockIdx.x * 128 + tid] = lds[tid] + lds[tid + 128];
}

// ---------------- Kernel 5: finalize BN scale/shift
__global__ void bn_pass2(const float* __restrict__ p2, const float* __restrict__ gamma,
                         const float* __restrict__ beta, float* __restrict__ bn)
{
    __shared__ float lds[128];
    const int t = threadIdx.x;
    float s = 0.f;
    for (int b = 0; b < 128; ++b) s += p2[b * 128 + t];
    lds[t] = s;
    __syncthreads();
    if (t < 64) {
        const float inv_n = 1.0f / (float)NPTS;
        const float mean = lds[t] * inv_n;
        const float var = lds[t + 64] * inv_n - mean * mean;
        const float scale = rsqrtf(var + 1e-5f) * gamma[t];
        bn[t] = scale;
        bn[64 + t] = beta[t] - mean * scale;   // conv bias cancels under BN; omitted
    }
}

// ---------------- Kernel 6a: y = silu(pre_bf16*scale + shift) -> f32 d_out
__global__ __launch_bounds__(256) void bn_silu_bf16_kernel(
    const __bf16* __restrict__ pre, float* __restrict__ out, const float* __restrict__ bn)
{
    __shared__ float s[128];
    if (threadIdx.x < 128) s[threadIdx.x] = bn[threadIdx.x];
    __syncthreads();
    const long M8 = (long)NPTS * 8;
    for (long i = (long)blockIdx.x * 256 + threadIdx.x; i < M8; i += (long)gridDim.x * 256) {
        const int c0 = ((int)i & 7) << 3;
        const bf16x8 v = __builtin_nontemporal_load((const bf16x8*)pre + i);
        f32x4 lo, hi;
#pragma unroll
        for (int j = 0; j < 4; ++j) {
            const float y = (float)v[j] * s[c0 + j] + s[64 + c0 + j];
            lo[j] = y * (1.0f / (1.0f + __expf(-y)));
        }
#pragma unroll
        for (int j = 0; j < 4; ++j) {
            const float y = (float)v[4 + j] * s[c0 + 4 + j] + s[64 + c0 + 4 + j];
            hi[j] = y * (1.0f / (1.0f + __expf(-y)));
        }
        f32x4* o = (f32x4*)out + i * 2;
        o[0] = lo; o[1] = hi;
    }
}

// ---------------- Kernel 6b: fallback, f32 pre-BN in-place on d_out
__global__ __launch_bounds__(256) void bn_silu_f32_kernel(
    float* __restrict__ out, const float* __restrict__ bn)
{
    __shared__ float s[128];
    if (threadIdx.x < 128) s[threadIdx.x] = bn[threadIdx.x];
    __syncthreads();
    f32x4* o4 = (f32x4*)out;
    const long M4 = (long)NPTS * 16;
    for (long i = (long)blockIdx.x * 256 + threadIdx.x; i < M4; i += (long)gridDim.x * 256) {
        const int c0 = ((int)i & 15) << 2;
        f32x4 v = __builtin_nontemporal_load(o4 + i);
#pragma unroll
        for (int j = 0; j < 4; ++j) {
            const float y = v[j] * s[c0 + j] + s[64 + c0 + j];
            v[j] = y * (1.0f / (1.0f + __expf(-y)));
        }
        o4[i] = v;
    }
}

extern "C" void kernel_launch(void* const* d_in, const int* in_sizes, int n_in,
                              void* d_out, int out_size, void* d_ws, size_t ws_size,
                              hipStream_t stream)
{
    const float* feats     = (const float*)d_in[0];
    const float* time_emb  = (const float*)d_in[1];
    const float* W         = (const float*)d_in[2];
    /* d_in[3] = bias: cancels exactly under training-mode BN -> unused */
    const float* gamma     = (const float*)d_in[4];
    const float* beta      = (const float*)d_in[5];
    const int*   batch_idx = (const int*)d_in[6];
    const int*   nbr_idx   = (const int*)d_in[7];
    const int*   nbr_valid = (const int*)d_in[8];
    float* out = (float*)d_out;

    char* ws = (char*)d_ws;
    size_t off = 0;
    auto take = [&](size_t bytes) { char* p = ws + off; off = (off + bytes + 255) & ~(size_t)255; return p; };
    __bf16* xh      = (__bf16*)take((size_t)NPTS * 32 * 2);          // 64 MB
    int* bounds     = (int*)take(9 * 4);
    __bf16* wlo     = (__bf16*)take((size_t)KOFF * 2048 * 2);        // 108 KB
    __bf16* twc     = (__bf16*)take((size_t)KOFF * 512 * 2);         // 27 KB
    float* partials = (float*)take((size_t)NWAVES * 128 * 4);        // 16 MB
    float* p2       = (float*)take(128 * 128 * 4);
    float* bn       = (float*)take(512);
    const size_t pre_bytes = (size_t)NPTS * 64 * 2;                  // 128 MB
    const bool bf16pre = (off + pre_bytes) <= ws_size;
    __bf16* pre = bf16pre ? (__bf16*)take(pre_bytes) : (__bf16*)0;

    hipLaunchKernelGGL(build_xh_kernel, dim3(31250), dim3(256), 0, stream, feats, xh);
    hipLaunchKernelGGL(prep_kernel, dim3(271), dim3(256), 0, stream,
                       W, time_emb, batch_idx, wlo, twc, bounds);
    if (bf16pre) {
        hipLaunchKernelGGL((conv_kernel<1>), dim3(NWG_CONV), dim3(CONV_BLOCK), 0, stream,
                           xh, bounds, wlo, twc, nbr_idx, nbr_valid, out, pre, partials);
    } else {
        hipLaunchKernelGGL((conv_kernel<0>), dim3(NWG_CONV), dim3(CONV_BLOCK), 0, stream,
                           xh, bounds, wlo, twc, nbr_idx, nbr_valid, out, pre, partials);
    }
    hipLaunchKernelGGL(bn_pass1, dim3(128), dim3(256), 0, stream, partials, p2);
    hipLaunchKernelGGL(bn_pass2, dim3(1), dim3(128), 0, stream, p2, gamma, beta, bn);
    if (bf16pre) {
        hipLaunchKernelGGL(bn_silu_bf16_kernel, dim3(2048), dim3(256), 0, stream, pre, out, bn);
    } else {
        hipLaunchKernelGGL(bn_silu_f32_kernel, dim3(2048), dim3(256), 0, stream, out, bn);
    }
}